// Round 4
// baseline (7811.761 us; speedup 1.0000x reference)
//
#include <hip/hip_runtime.h>

using short8 = __attribute__((ext_vector_type(8))) short;
using f32x4  = __attribute__((ext_vector_type(4))) float;

// ---------------- workspace layout ----------------
static constexpr size_t N_WF0 = (size_t)2*32*8*3*4*512;   // shorts
static constexpr size_t N_WF1 = (size_t)6*32*8*6*4*512;   // shorts
static constexpr size_t N_WF  = N_WF0 + N_WF1;
static constexpr size_t N_BSE = (size_t)8*2048;           // f32 bias sums
static constexpr size_t N_XPE = (size_t)128*2*256*8;      // shorts, embed k8-major [t][kg2][b][8]
static constexpr size_t N_HBE = (size_t)2*8*64*256*8;     // shorts, h dbuf [par][ld][kgrp][b][8]
static constexpr size_t N_CBE = (size_t)8*256*512;        // f32 final c [ld][b][j] (written at t=127)
static constexpr size_t N_FCT = (size_t)8192*64;          // f32 fc_w^T [k][o]
static constexpr size_t N_FL  = (size_t)8*128;            // int flags [plane][t]

static constexpr size_t OFF_WF = 0;
static constexpr size_t OFF_BS = OFF_WF + N_WF*2;
static constexpr size_t OFF_XP = OFF_BS + N_BSE*4;
static constexpr size_t OFF_HB = OFF_XP + N_XPE*2;
static constexpr size_t OFF_CB = OFF_HB + N_HBE*2;
static constexpr size_t OFF_HF = OFF_CB + N_CBE*4;
static constexpr size_t OFF_FC = OFF_HF + N_CBE*4;
static constexpr size_t OFF_FL = OFF_FC + N_FCT*4;
static constexpr size_t WS_NEEDED = OFF_FL + N_FL*4;      // ~59.8 MB

// LDS: A-stage dbuf [p][wv][sl][1024B] + red f32[8*4*16][20] + c f32[16][256]
static constexpr int LDS_A   = 2*8*6*1024;                // 98304
static constexpr int LDS_RED = 8*4*16*20*4;               // 40960
static constexpr int LDS_C   = 16*256*4;                  // 16384
static constexpr int LDS_TOT = LDS_A + LDS_RED + LDS_C;   // 155648 (152 KB)

__device__ __forceinline__ short f2bf(float f) {
  unsigned u = __float_as_uint(f);
  u += 0x7fff + ((u >> 16) & 1);   // RNE
  return (short)(u >> 16);
}

__device__ __forceinline__ void wait_ge(int* f, int target) {
  while (__hip_atomic_load(f, __ATOMIC_RELAXED, __HIP_MEMORY_SCOPE_AGENT) < target)
    __builtin_amdgcn_s_sleep(1);
}

__device__ __forceinline__ void dma16(const void* g, void* l) {
  __builtin_amdgcn_global_load_lds((const __attribute__((address_space(1))) unsigned int*)g,
                                   (__attribute__((address_space(3))) unsigned int*)l, 16, 0, 0);
}

// lgkmcnt(0) + raw s_barrier: does NOT drain vmcnt (keeps DMA pipeline alive)
__device__ __forceinline__ void lds_barrier() {
  __builtin_amdgcn_sched_barrier(0);
  __builtin_amdgcn_s_waitcnt(0xC07F);   // vmcnt=max, expcnt=7, lgkmcnt=0
  __builtin_amdgcn_s_barrier();
  __builtin_amdgcn_sched_barrier(0);
}

// ---------------- prep kernels ----------------
__global__ void k_prep_wf(const float* __restrict__ Wih0, const float* __restrict__ Whh0,
                          const float* __restrict__ Wih,  const float* __restrict__ Whh,
                          short* __restrict__ Wf) {
  size_t idx = (size_t)blockIdx.x * blockDim.x + threadIdx.x;
  if (idx >= N_WF) return;
  int j  = (int)(idx & 7);
  int lane = (int)((idx >> 3) & 63);
  int gt = (int)((idx >> 9) & 3);
  int lr = lane & 15, qq = lane >> 4;
  float v;
  if (idx < N_WF0) {
    size_t rest = idx >> 11;
    int sl = (int)(rest % 3); size_t r2 = rest / 3;
    int wvv = (int)(r2 & 7);  size_t r3 = r2 >> 3;
    int ncc = (int)(r3 & 31); int dd = (int)(r3 >> 5);
    int g = gt*512 + ncc*16 + lr;
    int k = (wvv*3 + sl)*32 + qq*8 + j;           // 0..767
    if (k < 16)       v = Wih0[((size_t)dd*2048 + g)*16 + k];
    else if (k < 64)  v = 0.f;
    else if (k < 576) v = Whh0[((size_t)dd*2048 + g)*512 + (k - 64)];
    else              v = 0.f;
  } else {
    size_t u = idx - N_WF0;
    size_t rest = u >> 11;
    int sl = (int)(rest % 6); size_t r2 = rest / 6;
    int wvv = (int)(r2 & 7);  size_t r3 = r2 >> 3;
    int ncc = (int)(r3 & 31); int ldm = (int)(r3 >> 5);   // (l-1)*2+d
    int g = gt*512 + ncc*16 + lr;
    int k = (wvv*6 + sl)*32 + qq*8 + j;           // 0..1535
    if (k < 1024) v = Wih[((size_t)ldm*2048 + g)*1024 + k];
    else          v = Whh[((size_t)ldm*2048 + g)*512 + (k - 1024)];
  }
  Wf[idx] = f2bf(v);
}

__global__ void k_prep_bias(const float* __restrict__ bih0, const float* __restrict__ bhh0,
                            const float* __restrict__ bih, const float* __restrict__ bhh,
                            float* __restrict__ bsum) {
  int idx = blockIdx.x * blockDim.x + threadIdx.x;
  if (idx >= (int)N_BSE) return;
  int g = idx & 2047;
  int dd = (idx >> 11) & 1;
  int ll = idx >> 12;
  float v;
  if (ll == 0) v = bih0[dd*2048 + g] + bhh0[dd*2048 + g];
  else         v = bih[((ll-1)*2 + dd)*2048 + g] + bhh[((ll-1)*2 + dd)*2048 + g];
  bsum[idx] = v;
}

__global__ void k_prep_xp(const int* __restrict__ tok, const float* __restrict__ embed,
                          short* __restrict__ XP) {
  int idx = blockIdx.x * blockDim.x + threadIdx.x;
  if (idx >= (int)N_XPE) return;
  int i  = idx & 7;
  int b  = (idx >> 3) & 255;
  int kg = (idx >> 11) & 1;
  int t  = idx >> 12;
  int k = kg*8 + i;                                // 0..15
  XP[idx] = f2bf(embed[tok[t*256 + b]*16 + k]);
}

__global__ void k_prep_fcT(const float* __restrict__ fc_w, float* __restrict__ fcT) {
  int idx = blockIdx.x * blockDim.x + threadIdx.x;
  if (idx >= (int)N_FCT) return;
  int o = idx & 63;
  int k = idx >> 6;
  fcT[idx] = fc_w[o * 8192 + k];
}

// ---------------- main recurrent kernel ----------------
// 256 blocks x 512 threads. block = (ld = blk&7 -> XCD, nc = blk>>3).
// Flag-synced layer-pipeline (no grid barrier). Weights in 96 VGPR/lane.
// A staged via async global_load_lds (no VGPR cost), dbuf at 16-batch rounds.
// c state lives in LDS (no global c traffic during recurrence).
__global__ void __launch_bounds__(512, 2)
k_lstm(const short* __restrict__ Wf, const float* __restrict__ bsum,
       const short* __restrict__ XP, short* __restrict__ hb,
       float* __restrict__ cF, float* __restrict__ hf, int* __restrict__ Fl) {
  extern __shared__ char smem[];
  char*  As  = smem;                                   // [p][wv][sl][1024]
  float* red = (float*)(smem + LDS_A);                 // idx ((wv*4+gt)*16+n)*20 + m
  float* cL  = (float*)(smem + LDS_A + LDS_RED);       // [ro*256 + e]

  const int blk = blockIdx.x;
  const int ld = blk & 7, nc = blk >> 3;
  const int l = ld >> 1, d = ld & 1;
  const int tid = threadIdx.x;
  const int wv = tid >> 6, lane = tid & 63;
  const int q = lane >> 4, lr = lane & 15;
  const int li = lane & 15, lk = lane >> 4;            // DMA lane -> (b, kgrp) offsets
  const int SL = (l == 0) ? 3 : 6;
  const int SUMW = (l == 0) ? 6 : 8;
  const bool act = (l > 0) || (wv < 6);
  const size_t HB_LD = 131072;                         // shorts per (par,ld) h-buffer

  // zero c
  for (int i = tid; i < 4096; i += 512) cL[i] = 0.f;

  // epilogue statics (threads 0..255)
  float b4[4];
  if (tid < 256) {
    int en = tid & 15;
    #pragma unroll
    for (int gt = 0; gt < 4; ++gt)
      b4[gt] = bsum[ld*2048 + gt*512 + nc*16 + en];
  }

  // ---- persistent weight registers (96 VGPR/lane) ----
  short8 wreg[6][4];
  {
    const short* wb = (l == 0)
      ? (Wf + (size_t)(d*32 + nc) * (8*3*4*512) + (size_t)wv * (3*4*512))
      : (Wf + N_WF0 + (size_t)((ld - 2)*32 + nc) * (8*6*4*512) + (size_t)wv * (6*4*512));
    #pragma unroll
    for (int sl = 0; sl < 6; ++sl) {
      #pragma unroll
      for (int gt = 0; gt < 4; ++gt) {
        if (sl < SL) wreg[sl][gt] = *(const short8*)(wb + (sl*4 + gt)*512 + lane*8);
        else         wreg[sl][gt] = short8{0,0,0,0,0,0,0,0};
      }
    }
  }
  __syncthreads();

  for (int t = 0; t < 128; ++t) {
    // ---- fine-grained waits (parallel polls on threads 0..4) ----
    if (tid == 0 && t > 0)           wait_ge(Fl + ld*128 + (t-1), 32);          // self
    if (tid == 1 && l > 0)           wait_ge(Fl + (ld-2-d)*128 + t, 32);        // prev dir0
    if (tid == 2 && l > 0)           wait_ge(Fl + (ld-1-d)*128 + t, 32);        // prev dir1
    if (tid == 3 && l < 3 && t >= 2) wait_ge(Fl + (2*l+2)*128 + (t-2), 32);     // backpressure
    if (tid == 4 && l < 3 && t >= 2) wait_ge(Fl + (2*l+3)*128 + (t-2), 32);
    __syncthreads();
    __builtin_amdgcn_fence(__ATOMIC_ACQUIRE, "agent");   // invalidate stale L1/L2

    const int pt = t & 1, pm = pt ^ 1;

    // per-lane DMA source pointers, one per slab
    const short* apl[6];
    #pragma unroll
    for (int sl = 0; sl < 6; ++sl) {
      if (sl < SL && act) {
        int S = wv * SL + sl;
        const short* p;
        if (l == 0) {
          if (S < 2) p = XP + (size_t)t*4096 + (size_t)(lk & 1)*2048;   // k>=16 hits zero weights
          else       p = hb + (size_t)(pm*8 + ld)*HB_LD + (size_t)(4*S - 8 + lk)*2048;
        } else {
          const int pl0 = ld - 2 - d;
          if (S < 16)      p = hb + (size_t)(pt*8 + pl0    )*HB_LD + (size_t)(4*S       + lk)*2048;
          else if (S < 32) p = hb + (size_t)(pt*8 + pl0 + 1)*HB_LD + (size_t)(4*S - 64  + lk)*2048;
          else             p = hb + (size_t)(pm*8 + ld     )*HB_LD + (size_t)(4*S - 128 + lk)*2048;
        }
        apl[sl] = p + li*8;
      } else apl[sl] = nullptr;
    }

    // prime round 0
    if (act) {
      #pragma unroll
      for (int sl = 0; sl < 6; ++sl)
        if (sl < SL) dma16(apl[sl], As + ((0*8 + wv)*6 + sl)*1024);
    }

    for (int ro = 0; ro < 16; ++ro) {
      if (act && ro < 15) {
        #pragma unroll
        for (int sl = 0; sl < 6; ++sl)
          if (sl < SL) dma16(apl[sl] + (ro+1)*128, As + ((((ro+1)&1)*8 + wv)*6 + sl)*1024);
      }
      __builtin_amdgcn_sched_barrier(0);
      if (act) {
        if (ro < 15) { if (l == 0) __builtin_amdgcn_s_waitcnt(0xF73);
                       else        __builtin_amdgcn_s_waitcnt(0xF76); }
        else         __builtin_amdgcn_s_waitcnt(0xF70);
      }
      __builtin_amdgcn_sched_barrier(0);

      if (act) {
        const char* ab = As + (size_t)(((ro&1)*8 + wv)*6)*1024 + (size_t)lane*16;
        f32x4 acc[4];
        #pragma unroll
        for (int gt = 0; gt < 4; ++gt) acc[gt] = f32x4{0.f,0.f,0.f,0.f};
        #pragma unroll
        for (int sl = 0; sl < 6; ++sl)
          if (sl < SL) {
            short8 af = *(const short8*)(ab + sl*1024);
            #pragma unroll
            for (int gt = 0; gt < 4; ++gt)
              acc[gt] = __builtin_amdgcn_mfma_f32_16x16x32_bf16(af, wreg[sl][gt], acc[gt], 0,0,0);
          }
        #pragma unroll
        for (int gt = 0; gt < 4; ++gt)
          *(f32x4*)&red[(((wv*4 + gt)*16) + lr)*20 + q*4] = acc[gt];
      }
      lds_barrier();

      if (tid < 256) {
        const int m  = tid >> 4;
        const int en = tid & 15;
        const int j  = nc*16 + en;
        const int b  = ro*16 + m;
        float g4[4];
        #pragma unroll
        for (int gt = 0; gt < 4; ++gt) {
          float s = 0.f;
          for (int w = 0; w < SUMW; ++w)
            s += red[((w*4 + gt)*16 + en)*20 + m];
          g4[gt] = s + b4[gt];
        }
        float cold = cL[ro*256 + tid];
        float si = 1.f/(1.f + __expf(-g4[0]));
        float sf = 1.f/(1.f + __expf(-g4[1]));
        float so = 1.f/(1.f + __expf(-g4[3]));
        float tg = 1.f - 2.f/(1.f + __expf(2.f*g4[2]));
        float cn = sf * cold + si * tg;
        float tc = 1.f - 2.f/(1.f + __expf(2.f*cn));
        float hn = so * tc;
        cL[ro*256 + tid] = cn;
        short* hw = hb + (size_t)(pt*8 + ld)*HB_LD;
        hw[((size_t)(j >> 3)*256 + b)*8 + (j & 7)] = f2bf(hn);
        if (t == 127) {
          hf[((size_t)ld*256 + b)*512 + j] = hn;
          cF[((size_t)ld*256 + b)*512 + j] = cn;
        }
      }
      if (ro < 15) lds_barrier();
      else         __syncthreads();   // full drain (stores visible) before release
    }

    if (tid == 0)
      __hip_atomic_fetch_add(Fl + ld*128 + t, 1, __ATOMIC_RELEASE, __HIP_MEMORY_SCOPE_AGENT);
  }
}

// ---------------- final FC + softmax ----------------
__global__ void __launch_bounds__(256)
k_fc(const float* __restrict__ hf, const float* __restrict__ cb,
     const float* __restrict__ fcT, const float* __restrict__ fc_b,
     float* __restrict__ out) {
  const int tid = threadIdx.x;
  const int o = tid & 63;
  const int qw = tid >> 6;
  const int bi = blockIdx.x * 4 + qw;
  __shared__ float hidc[4][128];
  float acc = 0.f;
  for (int k0 = 0; k0 < 8192; k0 += 128) {
    #pragma unroll
    for (int c = 0; c < 2; ++c) {
      int idx = tid + c * 256;                 // 0..511
      int r = idx >> 7, kk = idx & 127;
      int k = k0 + kk;
      int sS = k >> 10, rem = k & 1023, part = rem >> 9, j = rem & 511;
      const float* src = part ? cb : hf;       // hid = [h | c] per (l,d) slice
      hidc[r][kk] = src[((size_t)sS * 256 + (blockIdx.x * 4 + r)) * 512 + j];
    }
    __syncthreads();
    const float* hrow = hidc[qw];
    #pragma unroll 8
    for (int kk = 0; kk < 128; ++kk)
      acc += hrow[kk] * fcT[(size_t)(k0 + kk) * 64 + o];
    __syncthreads();
  }
  float v = acc + fc_b[o];
  float m = v;
  #pragma unroll
  for (int off = 32; off; off >>= 1) m = fmaxf(m, __shfl_xor(m, off, 64));
  float e = __expf(v - m);
  float ssum = e;
  #pragma unroll
  for (int off = 32; off; off >>= 1) ssum += __shfl_xor(ssum, off, 64);
  out[bi * 64 + o] = e / ssum;
}

// ---------------- launcher ----------------
extern "C" void kernel_launch(void* const* d_in, const int* in_sizes, int n_in,
                              void* d_out, int out_size, void* d_ws, size_t ws_size,
                              hipStream_t stream) {
  const int*   tok   = (const int*)d_in[0];
  const float* embed = (const float*)d_in[1];
  const float* Wih0  = (const float*)d_in[2];
  const float* Whh0  = (const float*)d_in[3];
  const float* bih0  = (const float*)d_in[4];
  const float* bhh0  = (const float*)d_in[5];
  const float* Wih   = (const float*)d_in[6];
  const float* Whh   = (const float*)d_in[7];
  const float* bih   = (const float*)d_in[8];
  const float* bhh   = (const float*)d_in[9];
  const float* fc_w  = (const float*)d_in[10];
  const float* fc_b  = (const float*)d_in[11];
  float* out = (float*)d_out;

  if (ws_size < WS_NEEDED) return;   // fail visibly (poison stays)

  char* ws = (char*)d_ws;
  short* Wfb  = (short*)(ws + OFF_WF);
  float* bsum = (float*)(ws + OFF_BS);
  short* XP   = (short*)(ws + OFF_XP);
  short* hbuf = (short*)(ws + OFF_HB);
  float* cFb  = (float*)(ws + OFF_CB);
  float* hfb  = (float*)(ws + OFF_HF);
  float* fcT  = (float*)(ws + OFF_FC);
  int*   flg  = (int*)  (ws + OFF_FL);

  // zero init: h parity-1 half (read as h_{t=-1}) and the flags
  hipMemsetAsync(ws + OFF_HB + N_HBE, 0, N_HBE, stream);
  hipMemsetAsync(ws + OFF_FL, 0, N_FL * 4, stream);

  k_prep_wf  <<<(int)((N_WF  + 255) / 256), 256, 0, stream>>>(Wih0, Whh0, Wih, Whh, Wfb);
  k_prep_bias<<<(int)((N_BSE + 255) / 256), 256, 0, stream>>>(bih0, bhh0, bih, bhh, bsum);
  k_prep_xp  <<<(int)((N_XPE + 255) / 256), 256, 0, stream>>>(tok, embed, XP);
  k_prep_fcT <<<(int)((N_FCT + 255) / 256), 256, 0, stream>>>(fc_w, fcT);

  static bool attr_set = false;
  (void)hipFuncSetAttribute((const void*)k_lstm,
                            hipFuncAttributeMaxDynamicSharedMemorySize, LDS_TOT);
  (void)attr_set;

  void* kargs[] = {(void*)&Wfb, (void*)&bsum, (void*)&XP,
                   (void*)&hbuf, (void*)&cFb, (void*)&hfb, (void*)&flg};
  hipLaunchCooperativeKernel((void*)k_lstm, dim3(256), dim3(512), kargs, LDS_TOT, stream);

  k_fc<<<64, 256, 0, stream>>>(hfb, cFb, fcT, fc_b, out);
}

// Round 5
// 5706.215 us; speedup vs baseline: 1.3690x; 1.3690x over previous
//
#include <hip/hip_runtime.h>

using short8 = __attribute__((ext_vector_type(8))) short;
using f32x4  = __attribute__((ext_vector_type(4))) float;

// ---------------- workspace layout ----------------
static constexpr size_t N_WF0 = (size_t)2*32*8*3*4*512;   // shorts
static constexpr size_t N_WF1 = (size_t)6*32*8*6*4*512;   // shorts
static constexpr size_t N_WF  = N_WF0 + N_WF1;
static constexpr size_t N_BSE = (size_t)8*2048;           // f32 bias sums
static constexpr size_t N_XPE = (size_t)128*2*256*8;      // shorts, embed k8-major [t][kg2][b][8]
static constexpr size_t N_HBE = (size_t)2*8*64*256*8;     // shorts, h dbuf [par][ld][kgrp][b][8]
static constexpr size_t N_CBE = (size_t)8*256*512;        // f32 final c [ld][b][j] (written at t=127)
static constexpr size_t N_FCT = (size_t)8192*64;          // f32 fc_w^T [k][o]
static constexpr size_t N_FL  = (size_t)8*128;            // int flags [plane][t]

static constexpr size_t OFF_WF = 0;
static constexpr size_t OFF_BS = OFF_WF + N_WF*2;
static constexpr size_t OFF_XP = OFF_BS + N_BSE*4;
static constexpr size_t OFF_HB = OFF_XP + N_XPE*2;
static constexpr size_t OFF_CB = OFF_HB + N_HBE*2;
static constexpr size_t OFF_HF = OFF_CB + N_CBE*4;
static constexpr size_t OFF_FC = OFF_HF + N_CBE*4;
static constexpr size_t OFF_FL = OFF_FC + N_FCT*4;
static constexpr size_t WS_NEEDED = OFF_FL + N_FL*4;      // ~59.8 MB

// LDS: A-stage dbuf [p][wv][sl][1024B] + red f32[8*4*16][20] + c f32[16][256]
static constexpr int LDS_A   = 2*8*6*1024;                // 98304
static constexpr int LDS_RED = 8*4*16*20*4;               // 40960
static constexpr int LDS_C   = 16*256*4;                  // 16384
static constexpr int LDS_TOT = LDS_A + LDS_RED + LDS_C;   // 155648 (152 KB)

__device__ __forceinline__ short f2bf(float f) {
  unsigned u = __float_as_uint(f);
  u += 0x7fff + ((u >> 16) & 1);   // RNE
  return (short)(u >> 16);
}

// relaxed system-scope poll: global_load sc0 sc1 (L3-fresh), NO fence emitted
__device__ __forceinline__ void wait_ge(int* f, int target) {
  while (__hip_atomic_load(f, __ATOMIC_RELAXED, __HIP_MEMORY_SCOPE_SYSTEM) < target)
    __builtin_amdgcn_s_sleep(1);
}

// async global->LDS, system-coherent read (sc0|sc1 = bypass L1+L2, fetch at L3):
// no acquire fence / L2 invalidate needed anywhere in the recurrent loop.
__device__ __forceinline__ void dma16(const void* g, void* l) {
  __builtin_amdgcn_global_load_lds((const __attribute__((address_space(1))) unsigned int*)g,
                                   (__attribute__((address_space(3))) unsigned int*)l, 16, 0, 17);
}

// lgkmcnt(0) + raw s_barrier: does NOT drain vmcnt (keeps DMA pipeline alive)
__device__ __forceinline__ void lds_barrier() {
  __builtin_amdgcn_sched_barrier(0);
  __builtin_amdgcn_s_waitcnt(0xC07F);   // vmcnt=max, expcnt=7, lgkmcnt=0
  __builtin_amdgcn_s_barrier();
  __builtin_amdgcn_sched_barrier(0);
}

// ---------------- prep kernels ----------------
__global__ void k_prep_wf(const float* __restrict__ Wih0, const float* __restrict__ Whh0,
                          const float* __restrict__ Wih,  const float* __restrict__ Whh,
                          short* __restrict__ Wf) {
  size_t idx = (size_t)blockIdx.x * blockDim.x + threadIdx.x;
  if (idx >= N_WF) return;
  int j  = (int)(idx & 7);
  int lane = (int)((idx >> 3) & 63);
  int gt = (int)((idx >> 9) & 3);
  int lr = lane & 15, qq = lane >> 4;
  float v;
  if (idx < N_WF0) {
    size_t rest = idx >> 11;
    int sl = (int)(rest % 3); size_t r2 = rest / 3;
    int wvv = (int)(r2 & 7);  size_t r3 = r2 >> 3;
    int ncc = (int)(r3 & 31); int dd = (int)(r3 >> 5);
    int g = gt*512 + ncc*16 + lr;
    int k = (wvv*3 + sl)*32 + qq*8 + j;           // 0..767
    if (k < 16)       v = Wih0[((size_t)dd*2048 + g)*16 + k];
    else if (k < 64)  v = 0.f;
    else if (k < 576) v = Whh0[((size_t)dd*2048 + g)*512 + (k - 64)];
    else              v = 0.f;
  } else {
    size_t u = idx - N_WF0;
    size_t rest = u >> 11;
    int sl = (int)(rest % 6); size_t r2 = rest / 6;
    int wvv = (int)(r2 & 7);  size_t r3 = r2 >> 3;
    int ncc = (int)(r3 & 31); int ldm = (int)(r3 >> 5);   // (l-1)*2+d
    int g = gt*512 + ncc*16 + lr;
    int k = (wvv*6 + sl)*32 + qq*8 + j;           // 0..1535
    if (k < 1024) v = Wih[((size_t)ldm*2048 + g)*1024 + k];
    else          v = Whh[((size_t)ldm*2048 + g)*512 + (k - 1024)];
  }
  Wf[idx] = f2bf(v);
}

__global__ void k_prep_bias(const float* __restrict__ bih0, const float* __restrict__ bhh0,
                            const float* __restrict__ bih, const float* __restrict__ bhh,
                            float* __restrict__ bsum) {
  int idx = blockIdx.x * blockDim.x + threadIdx.x;
  if (idx >= (int)N_BSE) return;
  int g = idx & 2047;
  int dd = (idx >> 11) & 1;
  int ll = idx >> 12;
  float v;
  if (ll == 0) v = bih0[dd*2048 + g] + bhh0[dd*2048 + g];
  else         v = bih[((ll-1)*2 + dd)*2048 + g] + bhh[((ll-1)*2 + dd)*2048 + g];
  bsum[idx] = v;
}

__global__ void k_prep_xp(const int* __restrict__ tok, const float* __restrict__ embed,
                          short* __restrict__ XP) {
  int idx = blockIdx.x * blockDim.x + threadIdx.x;
  if (idx >= (int)N_XPE) return;
  int i  = idx & 7;
  int b  = (idx >> 3) & 255;
  int kg = (idx >> 11) & 1;
  int t  = idx >> 12;
  int k = kg*8 + i;                                // 0..15
  XP[idx] = f2bf(embed[tok[t*256 + b]*16 + k]);
}

__global__ void k_prep_fcT(const float* __restrict__ fc_w, float* __restrict__ fcT) {
  int idx = blockIdx.x * blockDim.x + threadIdx.x;
  if (idx >= (int)N_FCT) return;
  int o = idx & 63;
  int k = idx >> 6;
  fcT[idx] = fc_w[o * 8192 + k];
}

// ---------------- main recurrent kernel ----------------
// 256 blocks x 512 threads. block = (ld = blk&7 -> XCD, nc = blk>>3).
// Flag-synced layer-pipeline; NO agent fences anywhere in the loop:
//   h stores  = relaxed system-scope atomic stores (sc0 sc1, write-through to L3)
//   A loads   = global_load_lds aux=17 (sc0|sc1, coherent read at L3)
//   flags     = relaxed system-scope atomics (poll loads bypass caches)
// __syncthreads() drains vmcnt before the flag add -> data ordered before flag.
__global__ void __launch_bounds__(512, 2)
k_lstm(const short* __restrict__ Wf, const float* __restrict__ bsum,
       const short* __restrict__ XP, short* __restrict__ hb,
       float* __restrict__ cF, float* __restrict__ hf, int* __restrict__ Fl) {
  extern __shared__ char smem[];
  char*  As  = smem;                                   // [p][wv][sl][1024]
  float* red = (float*)(smem + LDS_A);                 // idx ((wv*4+gt)*16+n)*20 + m
  float* cL  = (float*)(smem + LDS_A + LDS_RED);       // [ro*256 + e]

  const int blk = blockIdx.x;
  const int ld = blk & 7, nc = blk >> 3;
  const int l = ld >> 1, d = ld & 1;
  const int tid = threadIdx.x;
  const int wv = tid >> 6, lane = tid & 63;
  const int q = lane >> 4, lr = lane & 15;
  const int li = lane & 15, lk = lane >> 4;            // DMA lane -> (b, kgrp) offsets
  const int SL = (l == 0) ? 3 : 6;
  const int SUMW = (l == 0) ? 6 : 8;
  const bool act = (l > 0) || (wv < 6);
  const size_t HB_LD = 131072;                         // shorts per (par,ld) h-buffer

  // zero c
  for (int i = tid; i < 4096; i += 512) cL[i] = 0.f;

  // epilogue statics (threads 0..255)
  float b4[4];
  if (tid < 256) {
    int en = tid & 15;
    #pragma unroll
    for (int gt = 0; gt < 4; ++gt)
      b4[gt] = bsum[ld*2048 + gt*512 + nc*16 + en];
  }

  // ---- persistent weight registers (96 VGPR/lane) ----
  short8 wreg[6][4];
  {
    const short* wb = (l == 0)
      ? (Wf + (size_t)(d*32 + nc) * (8*3*4*512) + (size_t)wv * (3*4*512))
      : (Wf + N_WF0 + (size_t)((ld - 2)*32 + nc) * (8*6*4*512) + (size_t)wv * (6*4*512));
    #pragma unroll
    for (int sl = 0; sl < 6; ++sl) {
      #pragma unroll
      for (int gt = 0; gt < 4; ++gt) {
        if (sl < SL) wreg[sl][gt] = *(const short8*)(wb + (sl*4 + gt)*512 + lane*8);
        else         wreg[sl][gt] = short8{0,0,0,0,0,0,0,0};
      }
    }
  }
  __syncthreads();

  for (int t = 0; t < 128; ++t) {
    // ---- fine-grained waits (parallel polls on threads 0..4, no fences) ----
    if (tid == 0 && t > 0)           wait_ge(Fl + ld*128 + (t-1), 32);          // self
    if (tid == 1 && l > 0)           wait_ge(Fl + (ld-2-d)*128 + t, 32);        // prev dir0
    if (tid == 2 && l > 0)           wait_ge(Fl + (ld-1-d)*128 + t, 32);        // prev dir1
    if (tid == 3 && l < 3 && t >= 2) wait_ge(Fl + (2*l+2)*128 + (t-2), 32);     // backpressure
    if (tid == 4 && l < 3 && t >= 2) wait_ge(Fl + (2*l+3)*128 + (t-2), 32);
    __syncthreads();

    const int pt = t & 1, pm = pt ^ 1;

    // per-lane DMA source pointers, one per slab
    const short* apl[6];
    #pragma unroll
    for (int sl = 0; sl < 6; ++sl) {
      if (sl < SL && act) {
        int S = wv * SL + sl;
        const short* p;
        if (l == 0) {
          if (S < 2) p = XP + (size_t)t*4096 + (size_t)(lk & 1)*2048;   // k>=16 hits zero weights
          else       p = hb + (size_t)(pm*8 + ld)*HB_LD + (size_t)(4*S - 8 + lk)*2048;
        } else {
          const int pl0 = ld - 2 - d;
          if (S < 16)      p = hb + (size_t)(pt*8 + pl0    )*HB_LD + (size_t)(4*S       + lk)*2048;
          else if (S < 32) p = hb + (size_t)(pt*8 + pl0 + 1)*HB_LD + (size_t)(4*S - 64  + lk)*2048;
          else             p = hb + (size_t)(pm*8 + ld     )*HB_LD + (size_t)(4*S - 128 + lk)*2048;
        }
        apl[sl] = p + li*8;
      } else apl[sl] = nullptr;
    }

    // prime round 0
    if (act) {
      #pragma unroll
      for (int sl = 0; sl < 6; ++sl)
        if (sl < SL) dma16(apl[sl], As + ((0*8 + wv)*6 + sl)*1024);
    }

    for (int ro = 0; ro < 16; ++ro) {
      if (act && ro < 15) {
        #pragma unroll
        for (int sl = 0; sl < 6; ++sl)
          if (sl < SL) dma16(apl[sl] + (ro+1)*128, As + ((((ro+1)&1)*8 + wv)*6 + sl)*1024);
      }
      __builtin_amdgcn_sched_barrier(0);
      if (act) {
        if (ro < 15) { if (l == 0) __builtin_amdgcn_s_waitcnt(0xF73);
                       else        __builtin_amdgcn_s_waitcnt(0xF76); }
        else         __builtin_amdgcn_s_waitcnt(0xF70);
      }
      __builtin_amdgcn_sched_barrier(0);

      if (act) {
        const char* ab = As + (size_t)(((ro&1)*8 + wv)*6)*1024 + (size_t)lane*16;
        f32x4 acc[4];
        #pragma unroll
        for (int gt = 0; gt < 4; ++gt) acc[gt] = f32x4{0.f,0.f,0.f,0.f};
        #pragma unroll
        for (int sl = 0; sl < 6; ++sl)
          if (sl < SL) {
            short8 af = *(const short8*)(ab + sl*1024);
            #pragma unroll
            for (int gt = 0; gt < 4; ++gt)
              acc[gt] = __builtin_amdgcn_mfma_f32_16x16x32_bf16(af, wreg[sl][gt], acc[gt], 0,0,0);
          }
        #pragma unroll
        for (int gt = 0; gt < 4; ++gt)
          *(f32x4*)&red[(((wv*4 + gt)*16) + lr)*20 + q*4] = acc[gt];
      }
      lds_barrier();

      if (tid < 256) {
        const int m  = tid >> 4;
        const int en = tid & 15;
        const int j  = nc*16 + en;
        const int b  = ro*16 + m;
        float g4[4];
        #pragma unroll
        for (int gt = 0; gt < 4; ++gt) {
          float s = 0.f;
          for (int w = 0; w < SUMW; ++w)
            s += red[((w*4 + gt)*16 + en)*20 + m];
          g4[gt] = s + b4[gt];
        }
        float cold = cL[ro*256 + tid];
        float si = 1.f/(1.f + __expf(-g4[0]));
        float sf = 1.f/(1.f + __expf(-g4[1]));
        float so = 1.f/(1.f + __expf(-g4[3]));
        float tg = 1.f - 2.f/(1.f + __expf(2.f*g4[2]));
        float cn = sf * cold + si * tg;
        float tc = 1.f - 2.f/(1.f + __expf(2.f*cn));
        float hn = so * tc;
        cL[ro*256 + tid] = cn;
        short* hw = hb + (size_t)(pt*8 + ld)*HB_LD;
        // system-scope relaxed store: write-through (sc0 sc1), visible at L3
        __hip_atomic_store(&hw[((size_t)(j >> 3)*256 + b)*8 + (j & 7)], f2bf(hn),
                           __ATOMIC_RELAXED, __HIP_MEMORY_SCOPE_SYSTEM);
        if (t == 127) {
          hf[((size_t)ld*256 + b)*512 + j] = hn;
          cF[((size_t)ld*256 + b)*512 + j] = cn;
        }
      }
      if (ro < 15) lds_barrier();
      else         __syncthreads();   // drains vmcnt: h stores acked before flag
    }

    if (tid == 0)
      __hip_atomic_fetch_add(Fl + ld*128 + t, 1, __ATOMIC_RELAXED, __HIP_MEMORY_SCOPE_SYSTEM);
  }
}

// ---------------- final FC + softmax ----------------
__global__ void __launch_bounds__(256)
k_fc(const float* __restrict__ hf, const float* __restrict__ cb,
     const float* __restrict__ fcT, const float* __restrict__ fc_b,
     float* __restrict__ out) {
  const int tid = threadIdx.x;
  const int o = tid & 63;
  const int qw = tid >> 6;
  const int bi = blockIdx.x * 4 + qw;
  __shared__ float hidc[4][128];
  float acc = 0.f;
  for (int k0 = 0; k0 < 8192; k0 += 128) {
    #pragma unroll
    for (int c = 0; c < 2; ++c) {
      int idx = tid + c * 256;                 // 0..511
      int r = idx >> 7, kk = idx & 127;
      int k = k0 + kk;
      int sS = k >> 10, rem = k & 1023, part = rem >> 9, j = rem & 511;
      const float* src = part ? cb : hf;       // hid = [h | c] per (l,d) slice
      hidc[r][kk] = src[((size_t)sS * 256 + (blockIdx.x * 4 + r)) * 512 + j];
    }
    __syncthreads();
    const float* hrow = hidc[qw];
    #pragma unroll 8
    for (int kk = 0; kk < 128; ++kk)
      acc += hrow[kk] * fcT[(size_t)(k0 + kk) * 64 + o];
    __syncthreads();
  }
  float v = acc + fc_b[o];
  float m = v;
  #pragma unroll
  for (int off = 32; off; off >>= 1) m = fmaxf(m, __shfl_xor(m, off, 64));
  float e = __expf(v - m);
  float ssum = e;
  #pragma unroll
  for (int off = 32; off; off >>= 1) ssum += __shfl_xor(ssum, off, 64);
  out[bi * 64 + o] = e / ssum;
}

// ---------------- launcher ----------------
extern "C" void kernel_launch(void* const* d_in, const int* in_sizes, int n_in,
                              void* d_out, int out_size, void* d_ws, size_t ws_size,
                              hipStream_t stream) {
  const int*   tok   = (const int*)d_in[0];
  const float* embed = (const float*)d_in[1];
  const float* Wih0  = (const float*)d_in[2];
  const float* Whh0  = (const float*)d_in[3];
  const float* bih0  = (const float*)d_in[4];
  const float* bhh0  = (const float*)d_in[5];
  const float* Wih   = (const float*)d_in[6];
  const float* Whh   = (const float*)d_in[7];
  const float* bih   = (const float*)d_in[8];
  const float* bhh   = (const float*)d_in[9];
  const float* fc_w  = (const float*)d_in[10];
  const float* fc_b  = (const float*)d_in[11];
  float* out = (float*)d_out;

  if (ws_size < WS_NEEDED) return;   // fail visibly (poison stays)

  char* ws = (char*)d_ws;
  short* Wfb  = (short*)(ws + OFF_WF);
  float* bsum = (float*)(ws + OFF_BS);
  short* XP   = (short*)(ws + OFF_XP);
  short* hbuf = (short*)(ws + OFF_HB);
  float* cFb  = (float*)(ws + OFF_CB);
  float* hfb  = (float*)(ws + OFF_HF);
  float* fcT  = (float*)(ws + OFF_FC);
  int*   flg  = (int*)  (ws + OFF_FL);

  // zero init: h parity-1 half (read as h_{t=-1}) and the flags
  hipMemsetAsync(ws + OFF_HB + N_HBE, 0, N_HBE, stream);
  hipMemsetAsync(ws + OFF_FL, 0, N_FL * 4, stream);

  k_prep_wf  <<<(int)((N_WF  + 255) / 256), 256, 0, stream>>>(Wih0, Whh0, Wih, Whh, Wfb);
  k_prep_bias<<<(int)((N_BSE + 255) / 256), 256, 0, stream>>>(bih0, bhh0, bih, bhh, bsum);
  k_prep_xp  <<<(int)((N_XPE + 255) / 256), 256, 0, stream>>>(tok, embed, XP);
  k_prep_fcT <<<(int)((N_FCT + 255) / 256), 256, 0, stream>>>(fc_w, fcT);

  (void)hipFuncSetAttribute((const void*)k_lstm,
                            hipFuncAttributeMaxDynamicSharedMemorySize, LDS_TOT);

  void* kargs[] = {(void*)&Wfb, (void*)&bsum, (void*)&XP,
                   (void*)&hbuf, (void*)&cFb, (void*)&hfb, (void*)&flg};
  hipLaunchCooperativeKernel((void*)k_lstm, dim3(256), dim3(512), kargs, LDS_TOT, stream);

  k_fc<<<64, 256, 0, stream>>>(hfb, cFb, fcT, fc_b, out);
}